// Round 9
// baseline (92.979 us; speedup 1.0000x reference)
//
#include <hip/hip_runtime.h>
#include <hip/hip_fp16.h>

typedef __attribute__((ext_vector_type(8)))  _Float16 half8;
typedef __attribute__((ext_vector_type(16))) float    f32x16;

#define B_   16
#define NPTS 4096                      // points per batch (N == M == 4096)

constexpr int BLK  = 512;              // 8 waves
constexpr int QPB  = 128;              // queries per block (4 groups x 32)
constexpr int NQC  = NPTS / QPB;       // 32 query chunks
constexpr int RT   = 1024;             // targets staged per round (16 KB LDS)
constexpr int NR   = NPTS / RT;        // 4 rounds
constexpr int TPR  = RT / 32;          // 32 tiles of 32 targets per round
constexpr int NBLK = 2 * B_ * NQC;     // 1024 blocks

__device__ __forceinline__ float min3f(float a, float b, float c) {
    return fminf(fminf(a, b), c);      // -> v_min3_f32
}

// ------------------------------------------------------------------
// Fused MFMA chamfer, 8-wave blocks for 32 waves/CU. Block = (dir, b,
// 128-query chunk) x ALL targets. Wave = (query-group g = wv&3,
// target-half h = wv>>2): within each staged round of 32 tiles, wave
// takes tiles with (t&1)==h -> every wave active every round, halves
// merge in LDS at the end. Fragment layouts identical to R7/R8
// (verified absmax 0): B = [x,y,z,1,1,0,0,0] fp16 dup K-halves;
// A row = [-2x,-2y,-2z,g2hi,g2lo,0,0,0]; D = 2(|g|^2 - 2 q.g);
// d^2 = 0.5*minD + |q|^2 from the SAME fp16-rounded coords.
__global__ __launch_bounds__(BLK, 8) void chamfer_mfma(
        const float* __restrict__ pred, const float* __restrict__ gt,
        float* __restrict__ accum, unsigned* __restrict__ counter,
        float* __restrict__ out) {
    const int qc  = blockIdx.x;
    const int b   = blockIdx.y;
    const int dir = blockIdx.z;
    const float* qsrc = dir ? gt   : pred;   // queries
    const float* tsrc = dir ? pred : gt;     // targets

    __shared__ uint4 sh[RT];                 // 16 KB staged A-frag rows
    __shared__ float comb[2][QPB];           // cross-half merge
    __shared__ float q2s[QPB];               // per-query |q|^2
    __shared__ float ps[2];

    const int tid  = threadIdx.x;
    const int lane = tid & 63;
    const int wv   = tid >> 6;
    const int m    = lane & 31;
    const int g    = wv & 3;                 // query group
    const int h    = wv >> 2;                // target half (tile parity)

    // ---- B fragment: this lane's query (col = lane&31) ----
    const float* qp = qsrc + (b * NPTS + qc * QPB + g * 32 + m) * 3;
    __half hqx = __float2half(qp[0]);
    __half hqy = __float2half(qp[1]);
    __half hqz = __float2half(qp[2]);
    float fqx = __half2float(hqx), fqy = __half2float(hqy), fqz = __half2float(hqz);
    const float q2 = fmaf(fqx, fqx, fmaf(fqy, fqy, fqz * fqz));
    if (h == 0 && lane < 32) q2s[g * 32 + m] = q2;
    uint4 bu;
    bu.x = (unsigned)__half_as_ushort(hqx) | ((unsigned)__half_as_ushort(hqy) << 16);
    bu.y = (unsigned)__half_as_ushort(hqz) | (0x3C00u << 16);   // {z, 1.0}
    bu.z = 0x3C00u;                                             // {1.0, 0}
    bu.w = 0u;
    const half8 bfrag = __builtin_bit_cast(half8, bu);

    f32x16 zero;
#pragma unroll
    for (int i = 0; i < 16; ++i) zero[i] = 0.0f;

    float mn = 1e30f;

    for (int r = 0; r < NR; ++r) {
        if (r) __syncthreads();
        // ---- stage RT targets as A-frag rows (2 per thread) ----
        const float* tp = tsrc + (b * NPTS + r * RT) * 3;
#pragma unroll
        for (int k = 0; k < RT / BLK; ++k) {
            int j = k * BLK + tid;
            __half hx = __float2half(tp[3 * j + 0]);
            __half hy = __float2half(tp[3 * j + 1]);
            __half hz = __float2half(tp[3 * j + 2]);
            float fx = __half2float(hx), fy = __half2float(hy), fz = __half2float(hz);
            float g2 = fmaf(fx, fx, fmaf(fy, fy, fz * fz));
            __half ax = __float2half(-2.0f * fx);
            __half ay = __float2half(-2.0f * fy);
            __half az = __float2half(-2.0f * fz);
            __half g2hi = __float2half(g2);
            __half g2lo = __float2half(g2 - __half2float(g2hi));
            uint4 w;
            w.x = (unsigned)__half_as_ushort(ax) | ((unsigned)__half_as_ushort(ay) << 16);
            w.y = (unsigned)__half_as_ushort(az) | ((unsigned)__half_as_ushort(g2hi) << 16);
            w.z = (unsigned)__half_as_ushort(g2lo);
            w.w = 0u;
            sh[j] = w;
        }
        __syncthreads();

        // ---- this wave: 16 tiles of its parity within the round ----
#pragma unroll 8
        for (int t = h; t < TPR; t += 2) {
            uint4 au = sh[t * 32 + m];       // lanes L, L+32 share addr (free 2-way)
            half8 afrag = __builtin_bit_cast(half8, au);
            f32x16 d = __builtin_amdgcn_mfma_f32_32x32x16_f16(afrag, bfrag, zero, 0, 0, 0);
            float m0 = min3f(d[0],  d[1],  d[2]);
            float m1 = min3f(d[3],  d[4],  d[5]);
            float m2 = min3f(d[6],  d[7],  d[8]);
            float m3 = min3f(d[9],  d[10], d[11]);
            float m4 = min3f(d[12], d[13], d[14]);
            float n0 = min3f(m0, m1, m2);
            float n1 = min3f(m3, m4, d[15]);
            mn = min3f(mn, n0, n1);
        }
    }

    // rows split across lane halves: full 32-row min needs lane ^ 32
    float v = fminf(mn, __shfl_xor(mn, 32));
    comb[h][g * 32 + m] = v;                 // both lane-halves write same value
    __syncthreads();

    // merge halves, fold |q|^2, sqrt, block-sum (threads 0..127)
    float s = 0.0f;
    if (tid < QPB) {
        float vv = fminf(comb[0][tid], comb[1][tid]);
        float dd = fmaxf(fmaf(0.5f, vv, q2s[tid]), 0.0f);
        s = sqrtf(dd);
    }
    if (wv < 2) {
#pragma unroll
        for (int off = 32; off; off >>= 1) s += __shfl_xor(s, off);
        if (lane == 0) ps[wv] = s;
    }
    __syncthreads();

    if (tid == 0) {
        atomicAdd(accum, ps[0] + ps[1]);
        __threadfence();
        if (atomicAdd(counter, 1u) == NBLK - 1) {   // last block finalizes
            float total = atomicAdd(accum, 0.0f);   // coherent read
            float loss  = total * (1.0f / (float)(B_ * NPTS));
            out[0] = loss;          // WEIGHT * loss, WEIGHT = 1
            out[1] = loss;          // helper_loss
            out[2] = 0.1f * loss;   // helper_cderr = p1 chamfer * xyz_unit
        }
    }
}

// ------------------------------------------------------------------
extern "C" void kernel_launch(void* const* d_in, const int* in_sizes, int n_in,
                              void* d_out, int out_size, void* d_ws, size_t ws_size,
                              hipStream_t stream) {
    const float* pred = (const float*)d_in[0];
    const float* gt   = (const float*)d_in[1];
    float*    out     = (float*)d_out;
    float*    accum   = (float*)d_ws;
    unsigned* counter = (unsigned*)d_ws + 1;

    hipMemsetAsync(d_ws, 0, 8, stream);
    chamfer_mfma<<<dim3(NQC, B_, 2), BLK, 0, stream>>>(pred, gt, accum, counter, out);
}